// Round 2
// baseline (138.479 us; speedup 1.0000x reference)
//
#include <hip/hip_runtime.h>
#include <cstdint>
#include <cstring>

#define BATCH   4096
#define DIM     128
#define NLAYERS 8
#define KNODES  8
#define NDEG    4
#define NNODES  65
#define NODE_ELEMS (BATCH * DIM)  // 524288

typedef float    f32x4 __attribute__((ext_vector_type(4)));
typedef short    s16x8 __attribute__((ext_vector_type(8)));
typedef uint32_t u32x4 __attribute__((ext_vector_type(4)));

struct LayerSrcs { int p[KNODES][NDEG]; };

// ---------------- device helpers ----------------
__device__ __forceinline__ float bf_lo(uint32_t u) {
  union { uint32_t i; float f; } x; x.i = u << 16; return x.f;
}
__device__ __forceinline__ float bf_hi(uint32_t u) {
  union { uint32_t i; float f; } x; x.i = u & 0xffff0000u; return x.f;
}
__device__ __forceinline__ uint32_t f2bf(float f) {   // RNE round to bf16 (low 16 bits)
  union { float f; uint32_t i; } x; x.f = f;
  return (x.i + 0x7fffu + ((x.i >> 16) & 1u)) >> 16;
}
__device__ __forceinline__ uint32_t pack2(float a, float b) {
  return f2bf(a) | (f2bf(b) << 16);
}

// ---------------- kernels ----------------

// Convert W_all f32 -> bf16 (65*128*128 elems, 8 per thread, grid 520x256)
__global__ __launch_bounds__(256)
void conv_w(const float* __restrict__ W, uint16_t* __restrict__ Wb) {
  size_t idx = ((size_t)blockIdx.x * 256 + threadIdx.x) * 8;
  f32x4 v0 = *(const f32x4*)(W + idx);
  f32x4 v1 = *(const f32x4*)(W + idx + 4);
  u32x4 pk;
  pk.x = pack2(v0.x, v0.y); pk.y = pack2(v0.z, v0.w);
  pk.z = pack2(v1.x, v1.y); pk.w = pack2(v1.z, v1.w);
  *(u32x4*)(Wb + idx) = pk;
}

// One node-tile GEMM: out[node][rows] = relu( (sum parents) @ W[node]^T + b[node] )
// ROOT=1: single node 0, A = X (f32), grid 32.  ROOT=0: grid 256 = 8 nodes x 32 tiles.
template <int ROOT>
__global__ __launch_bounds__(256)
void node_gemm(const uint16_t* __restrict__ outs_r,
               uint16_t* __restrict__ outs_w,
               const uint16_t* __restrict__ Wb,
               const float* __restrict__ bias_all,
               const float* __restrict__ X,
               LayerSrcs srcs, int node_base)
{
  __shared__ char Alds[128 * 256];
  __shared__ char Blds[128 * 256];

  const int t = threadIdx.x;
  int k, tile;
  if (ROOT) { k = 0; tile = blockIdx.x; }
  else      { k = blockIdx.x & 7; tile = blockIdx.x >> 3; }
  const int node = node_base + k;
  const int row0 = tile * 128;

  const char* wsrc = (const char*)(Wb + (size_t)node * (DIM * DIM));

  const uint16_t* psrc[NDEG];
  if (!ROOT) {
#pragma unroll
    for (int p = 0; p < NDEG; ++p)
      psrc[p] = outs_r + (size_t)srcs.p[k][p] * NODE_ELEMS;
  }

  // ---- stage A (gather-sum parents -> bf16) and B (=W[node]) into swizzled LDS ----
#pragma unroll
  for (int it = 0; it < 8; ++it) {
    const int lin   = it * 256 + t;         // 0..2047: 16B chunk id
    const int r     = lin >> 4;             // row 0..127
    const int c0    = (lin & 15) << 3;      // first element of chunk
    const int lbyte = lin << 4;             // linear byte offset (r*256 + c0*2)
    const int sbyte = lbyte ^ ((r & 7) << 4);  // G4 XOR swizzle

    float a0, a1, a2, a3, a4, a5, a6, a7;
    if (ROOT) {
      const float* xp = X + (size_t)(row0 + r) * DIM + c0;
      f32x4 v0 = *(const f32x4*)xp;
      f32x4 v1 = *(const f32x4*)(xp + 4);
      a0 = v0.x; a1 = v0.y; a2 = v0.z; a3 = v0.w;
      a4 = v1.x; a5 = v1.y; a6 = v1.z; a7 = v1.w;
    } else {
      a0 = a1 = a2 = a3 = a4 = a5 = a6 = a7 = 0.f;
#pragma unroll
      for (int p = 0; p < NDEG; ++p) {
        u32x4 v = *(const u32x4*)(psrc[p] + (size_t)(row0 + r) * DIM + c0);
        a0 += bf_lo(v.x); a1 += bf_hi(v.x);
        a2 += bf_lo(v.y); a3 += bf_hi(v.y);
        a4 += bf_lo(v.z); a5 += bf_hi(v.z);
        a6 += bf_lo(v.w); a7 += bf_hi(v.w);
      }
    }
    u32x4 pk;
    pk.x = pack2(a0, a1); pk.y = pack2(a2, a3);
    pk.z = pack2(a4, a5); pk.w = pack2(a6, a7);
    *(u32x4*)(Alds + sbyte) = pk;

    *(u32x4*)(Blds + sbyte) = *(const u32x4*)(wsrc + lbyte);
  }
  __syncthreads();

  // ---- MFMA: each wave computes 32 rows x 128 cols ----
  const int lane = t & 63;
  const int w    = t >> 6;
  const int lr   = lane & 15;
  const int lg   = lane >> 4;

  f32x4 acc[2][8];
#pragma unroll
  for (int m = 0; m < 2; ++m)
#pragma unroll
    for (int n = 0; n < 8; ++n)
      acc[m][n] = (f32x4){0.f, 0.f, 0.f, 0.f};

#pragma unroll
  for (int ks = 0; ks < 4; ++ks) {
    const int kb = ks * 64 + lg * 16;       // byte offset of this lane's 8 k-elems
    s16x8 af[2], bfr[8];
#pragma unroll
    for (int m = 0; m < 2; ++m) {
      int r = w * 32 + m * 16 + lr;
      af[m] = *(const s16x8*)(Alds + ((r * 256 + kb) ^ ((r & 7) << 4)));
    }
#pragma unroll
    for (int n = 0; n < 8; ++n) {
      int e = n * 16 + lr;
      bfr[n] = *(const s16x8*)(Blds + ((e * 256 + kb) ^ ((e & 7) << 4)));
    }
#pragma unroll
    for (int m = 0; m < 2; ++m)
#pragma unroll
      for (int n = 0; n < 8; ++n)
        acc[m][n] = __builtin_amdgcn_mfma_f32_16x16x32_bf16(af[m], bfr[n], acc[m][n], 0, 0, 0);
  }

  // ---- epilogue: + bias, relu, bf16 store ----
  uint16_t* dst = outs_w + (size_t)node * NODE_ELEMS;
  const float* bp = bias_all + (size_t)node * DIM;
#pragma unroll
  for (int n = 0; n < 8; ++n) {
    const int col = n * 16 + lr;
    const float bv = bp[col];
#pragma unroll
    for (int m = 0; m < 2; ++m) {
      const int rb = row0 + w * 32 + m * 16 + lg * 4;
#pragma unroll
      for (int j = 0; j < 4; ++j) {
        float v = fmaxf(acc[m][n][j] + bv, 0.f);
        dst[(size_t)(rb + j) * DIM + col] = (uint16_t)f2bf(v);
      }
    }
  }
}

// Mean of last 8 node outputs -> f32 out. grid 256x256, 8 elems/thread.
__global__ __launch_bounds__(256)
void mean_last(const uint16_t* __restrict__ outs, float* __restrict__ out) {
  const size_t eoff = ((size_t)blockIdx.x * 256 + threadIdx.x) * 8;
  float a0 = 0, a1 = 0, a2 = 0, a3 = 0, a4 = 0, a5 = 0, a6 = 0, a7 = 0;
#pragma unroll
  for (int n = NNODES - KNODES; n < NNODES; ++n) {
    u32x4 v = *(const u32x4*)(outs + (size_t)n * NODE_ELEMS + eoff);
    a0 += bf_lo(v.x); a1 += bf_hi(v.x);
    a2 += bf_lo(v.y); a3 += bf_hi(v.y);
    a4 += bf_lo(v.z); a5 += bf_hi(v.z);
    a6 += bf_lo(v.w); a7 += bf_hi(v.w);
  }
  f32x4 o0 = {a0 * 0.125f, a1 * 0.125f, a2 * 0.125f, a3 * 0.125f};
  f32x4 o1 = {a4 * 0.125f, a5 * 0.125f, a6 * 0.125f, a7 * 0.125f};
  *(f32x4*)(out + eoff)     = o0;
  *(f32x4*)(out + eoff + 4) = o1;
}

// ---------------- host: replicate np.random.default_rng(0) graph ----------------
namespace nprng {
static inline uint32_t hashmix(uint32_t v, uint32_t& hc) {
  v ^= hc; hc *= 0x931e8875u; v *= hc; v ^= v >> 16; return v;
}
static inline uint32_t mixf(uint32_t x, uint32_t y) {
  // numpy bit_generator.pyx mix(): x*MIX_MULT_L - y*MIX_MULT_R, then xorshift
  uint32_t r = x * 0xca01f9ddu - y * 0x4973f715u;
  r ^= r >> 16;
  return r;
}
struct Pcg {
  unsigned __int128 state, inc;
  bool has32; uint32_t saved;
  void step() {
    const unsigned __int128 MUL =
        ((unsigned __int128)2549297995355413924ULL << 64) | 4865540595714422341ULL;
    state = state * MUL + inc;
  }
  void init_seed0() {
    // SeedSequence(0): entropy = [0], pool_size = 4
    uint32_t pool[4];
    uint32_t hc = 0x43b0d7e5u;  // INIT_A
    for (int i = 0; i < 4; ++i) pool[i] = hashmix(0u, hc);  // entropy[0]=0, then 0-fill
    for (int s = 0; s < 4; ++s)
      for (int d = 0; d < 4; ++d)
        if (s != d) pool[d] = mixf(pool[d], hashmix(pool[s], hc));
    // generate_state(4, uint64) -> 8 x uint32, little-endian pairs
    uint32_t st[8];
    uint32_t hb = 0x8b51f9ddu;  // INIT_B
    int cyc = 0;
    for (int i = 0; i < 8; ++i) {
      uint32_t dv = pool[cyc]; cyc = (cyc + 1) & 3;
      dv ^= hb; hb *= 0x58f38dedu; dv *= hb; dv ^= dv >> 16;
      st[i] = dv;
    }
    uint64_t v[4];
    for (int i = 0; i < 4; ++i)
      v[i] = (uint64_t)st[2 * i] | ((uint64_t)st[2 * i + 1] << 32);
    unsigned __int128 s128 = ((unsigned __int128)v[0] << 64) | v[1];
    unsigned __int128 i128 = ((unsigned __int128)v[2] << 64) | v[3];
    state = 0; inc = (i128 << 1) | 1;
    step(); state += s128; step();
    has32 = false; saved = 0;
  }
  uint64_t next64() {
    step();
    uint64_t rot = (uint64_t)(state >> 122);
    uint64_t x = (uint64_t)(state >> 64) ^ (uint64_t)state;
    return rot ? ((x >> rot) | (x << (64 - rot))) : x;
  }
  uint32_t next32() {  // numpy pcg64_next32: low half first, buffer high half
    if (has32) { has32 = false; return saved; }
    uint64_t v = next64();
    has32 = true; saved = (uint32_t)(v >> 32);
    return (uint32_t)v;
  }
  uint32_t lemire32(uint32_t rng_incl) {  // buffered_bounded_lemire_uint32
    uint32_t rng_excl = rng_incl + 1u;
    uint64_t m = (uint64_t)next32() * (uint64_t)rng_excl;
    uint32_t leftover = (uint32_t)m;
    if (leftover < rng_excl) {
      uint32_t threshold = (0xFFFFFFFFu - rng_incl) % rng_excl;
      while (leftover < threshold) {
        m = (uint64_t)next32() * (uint64_t)rng_excl;
        leftover = (uint32_t)m;
      }
    }
    return (uint32_t)(m >> 32);
  }
};
}  // namespace nprng

extern "C" void kernel_launch(void* const* d_in, const int* in_sizes, int n_in,
                              void* d_out, int out_size, void* d_ws, size_t ws_size,
                              hipStream_t stream) {
  const float* X    = (const float*)d_in[0];
  const float* W    = (const float*)d_in[1];
  const float* bias = (const float*)d_in[2];
  float* out        = (float*)d_out;

  uint16_t* Wb   = (uint16_t*)d_ws;
  uint16_t* outs = (uint16_t*)((char*)d_ws + (size_t)NNODES * DIM * DIM * 2);

  // Rebuild the deterministic graph (same every call; host-only work).
  nprng::Pcg rng; rng.init_seed0();
  LayerSrcs srcs[NLAYERS];
  int n_prev = 1;
  for (int l = 0; l < NLAYERS; ++l) {
    for (int k = 0; k < KNODES; ++k)
      for (int j = 0; j < NDEG; ++j)
        srcs[l].p[k][j] = (n_prev == 1) ? 0 : (int)rng.lemire32((uint32_t)(n_prev - 1));
    n_prev += KNODES;
  }

  conv_w<<<dim3(520), dim3(256), 0, stream>>>(W, Wb);

  LayerSrcs zero{};
  node_gemm<1><<<dim3(32), dim3(256), 0, stream>>>(outs, outs, Wb, bias, X, zero, 0);

  for (int l = 0; l < NLAYERS; ++l) {
    node_gemm<0><<<dim3(256), dim3(256), 0, stream>>>(outs, outs, Wb, bias, nullptr,
                                                      srcs[l], 1 + l * KNODES);
  }

  mean_last<<<dim3(256), dim3(256), 0, stream>>>(outs, out);
}

// Round 3
// 125.638 us; speedup vs baseline: 1.1022x; 1.1022x over previous
//
#include <hip/hip_runtime.h>
#include <cstdint>
#include <cstring>

#define BATCH   4096
#define DIM     128
#define NLAYERS 8
#define KNODES  8
#define NDEG    4
#define NNODES  65
#define NODE_ELEMS (BATCH * DIM)   // 524288 elems
#define ROWS    16                  // rows per block tile
#define SLOTS   35                  // LDS-resident activation slots
#define TILE_B  (ROWS * 256)        // 4096 bytes per bf16 tile (16 rows x 128 cols)
#define NTHREADS 512

typedef float    f32x4 __attribute__((ext_vector_type(4)));
typedef short    s16x8 __attribute__((ext_vector_type(8)));
typedef uint32_t u32x4 __attribute__((ext_vector_type(4)));

struct LayerSrcs { int p[KNODES][NDEG]; };

struct Sched {
  uint64_t pinfo[NLAYERS * KNODES];  // per node: 4 x {slot+1 (8b), src node id (8b)}
  int8_t   dst[NLAYERS * KNODES];    // >=0 LDS slot, -1 global spill, -2 mean-only, -3 dead
  int8_t   root_dst;
};

// ---------------- device helpers ----------------
__device__ __forceinline__ float bf_lo(uint32_t u) {
  union { uint32_t i; float f; } x; x.i = u << 16; return x.f;
}
__device__ __forceinline__ float bf_hi(uint32_t u) {
  union { uint32_t i; float f; } x; x.i = u & 0xffff0000u; return x.f;
}
__device__ __forceinline__ uint32_t f2bf(float f) {   // RNE round to bf16
  union { float f; uint32_t i; } x; x.f = f;
  return (x.i + 0x7fffu + ((x.i >> 16) & 1u)) >> 16;
}
__device__ __forceinline__ uint32_t pack2(float a, float b) {
  return f2bf(a) | (f2bf(b) << 16);
}

// ---------------- W pre-pack: f32 row-major -> bf16 MFMA-fragment-linear ----------------
// Wp chunk gid = ((node*4 + ks)*8 + n)*64 + lane ; 16B per chunk.
// element e of chunk = W[node][col = n*16 + (lane&15)][k = ks*32 + (lane>>4)*8 + e]
__global__ __launch_bounds__(256)
void pack_w(const float* __restrict__ W, uint16_t* __restrict__ Wp) {
  int gid  = blockIdx.x * 256 + threadIdx.x;     // 65*2048 = 133120 total
  int lane = gid & 63;
  int n    = (gid >> 6) & 7;
  int ks   = (gid >> 9) & 3;
  int node = gid >> 11;
  int col  = n * 16 + (lane & 15);
  int k0   = ks * 32 + (lane >> 4) * 8;
  const float* src = W + ((size_t)node * DIM + col) * DIM + k0;
  f32x4 v0 = *(const f32x4*)src;
  f32x4 v1 = *(const f32x4*)(src + 4);
  u32x4 pk;
  pk.x = pack2(v0.x, v0.y); pk.y = pack2(v0.z, v0.w);
  pk.z = pack2(v1.x, v1.y); pk.w = pack2(v1.z, v1.w);
  *(u32x4*)(Wp + (size_t)gid * 8) = pk;
}

// ---------------- per-node GEMM from A_sum scratch ----------------
__device__ __forceinline__ void gemm_node(
    char* lds, int sbuf, int n, int dstv,
    const uint16_t* __restrict__ Wp, const float* __restrict__ bias,
    uint16_t* __restrict__ outs, float* macc,
    int row0, int lane, int w, int lr, int lg)
{
  if (dstv == -3) return;  // dead node (uniform per block)
  const char* sb = lds + (size_t)(SLOTS + sbuf) * TILE_B;
  s16x8 af[4], wf[4];
#pragma unroll
  for (int ks = 0; ks < 4; ++ks) {
    af[ks] = *(const s16x8*)(sb + ((lr * 256 + ks * 64 + lg * 16) ^ ((lr & 7) << 4)));
    wf[ks] = *(const s16x8*)(Wp + ((((size_t)n * 4 + ks) * 8 + w) << 9) + lane * 8);
  }
  f32x4 acc = (f32x4){0.f, 0.f, 0.f, 0.f};
#pragma unroll
  for (int ks = 0; ks < 4; ++ks)
    acc = __builtin_amdgcn_mfma_f32_16x16x32_bf16(af[ks], wf[ks], acc, 0, 0, 0);

  const int col = w * 16 + lr;          // D: col = lane&15 side (W rows), row = A side
  const float bv = bias[(size_t)n * DIM + col];
  if (dstv >= 0) {
    char* db = lds + (size_t)dstv * TILE_B;
#pragma unroll
    for (int j = 0; j < 4; ++j) {
      int row = lg * 4 + j;
      float v = fmaxf(acc[j] + bv, 0.f);
      *(uint16_t*)(db + ((row * 256 + col * 2) ^ ((row & 7) << 4))) = (uint16_t)f2bf(v);
    }
  } else if (dstv == -1) {              // global spill
    uint16_t* gb = outs + (size_t)n * NODE_ELEMS + (size_t)row0 * DIM + col;
#pragma unroll
    for (int j = 0; j < 4; ++j) {
      int row = lg * 4 + j;
      float v = fmaxf(acc[j] + bv, 0.f);
      gb[(size_t)row * DIM] = (uint16_t)f2bf(v);
      gb += 0;  // keep gb base; index below
      // (explicit index to avoid pointer bump confusion)
    }
    // rewritten without the loop-carried trick:
  } else {                              // -2: mean accumulate (layer 8)
#pragma unroll
    for (int j = 0; j < 4; ++j)
      macc[j] += 0.125f * fmaxf(acc[j] + bv, 0.f);
  }
}

// NOTE: the dstv==-1 branch above writes row 0 repeatedly due to the edit above;
// real implementation below in dag_exec uses gemm_node2 with correct spill path.

__device__ __forceinline__ void gemm_node2(
    char* lds, int sbuf, int n, int dstv,
    const uint16_t* __restrict__ Wp, const float* __restrict__ bias,
    uint16_t* __restrict__ outs, float* macc,
    int row0, int lane, int w, int lr, int lg)
{
  if (dstv == -3) return;
  const char* sb = lds + (size_t)(SLOTS + sbuf) * TILE_B;
  s16x8 af[4], wf[4];
#pragma unroll
  for (int ks = 0; ks < 4; ++ks) {
    af[ks] = *(const s16x8*)(sb + ((lr * 256 + ks * 64 + lg * 16) ^ ((lr & 7) << 4)));
    wf[ks] = *(const s16x8*)(Wp + ((((size_t)n * 4 + ks) * 8 + w) << 9) + lane * 8);
  }
  f32x4 acc = (f32x4){0.f, 0.f, 0.f, 0.f};
#pragma unroll
  for (int ks = 0; ks < 4; ++ks)
    acc = __builtin_amdgcn_mfma_f32_16x16x32_bf16(af[ks], wf[ks], acc, 0, 0, 0);

  const int col = w * 16 + lr;
  const float bv = bias[(size_t)n * DIM + col];
  if (dstv >= 0) {
    char* db = lds + (size_t)dstv * TILE_B;
#pragma unroll
    for (int j = 0; j < 4; ++j) {
      int row = lg * 4 + j;
      float v = fmaxf(acc[j] + bv, 0.f);
      *(uint16_t*)(db + ((row * 256 + col * 2) ^ ((row & 7) << 4))) = (uint16_t)f2bf(v);
    }
  } else if (dstv == -1) {
    uint16_t* gb = outs + (size_t)n * NODE_ELEMS + (size_t)row0 * DIM + col;
#pragma unroll
    for (int j = 0; j < 4; ++j) {
      int row = lg * 4 + j;
      float v = fmaxf(acc[j] + bv, 0.f);
      gb[(size_t)row * DIM] = (uint16_t)f2bf(v);
    }
  } else {
#pragma unroll
    for (int j = 0; j < 4; ++j)
      macc[j] += 0.125f * fmaxf(acc[j] + bv, 0.f);
  }
}

// ---------------- the persistent DAG executor ----------------
__global__ __launch_bounds__(NTHREADS)
void dag_exec(const float* __restrict__ X, const uint16_t* __restrict__ Wp,
              const float* __restrict__ bias, uint16_t* __restrict__ outs,
              float* __restrict__ out, Sched sch)
{
  __shared__ char lds[(SLOTS + 4) * TILE_B];   // 35 slots + 4 A_sum scratch = 156 KB
  const int t    = threadIdx.x;
  const int lane = t & 63;
  const int w    = t >> 6;       // wave id = output-col panel (8 x 16 cols)
  const int lr   = lane & 15;
  const int lg   = lane >> 4;
  const int row0 = blockIdx.x * ROWS;

  float macc[4] = {0.f, 0.f, 0.f, 0.f};

  // ---- root: stage bf16(X tile) into scratch 0, then GEMM node 0 ----
  if (t < ROWS * 16) {
    int r = t >> 4, c = t & 15;
    const float* xp = X + (size_t)(row0 + r) * DIM + c * 8;
    f32x4 v0 = *(const f32x4*)xp;
    f32x4 v1 = *(const f32x4*)(xp + 4);
    u32x4 pk;
    pk.x = pack2(v0.x, v0.y); pk.y = pack2(v0.z, v0.w);
    pk.z = pack2(v1.x, v1.y); pk.w = pack2(v1.z, v1.w);
    int off = (r * 256 + c * 16) ^ ((r & 7) << 4);
    *(u32x4*)(lds + (size_t)SLOTS * TILE_B + off) = pk;
  }
  __syncthreads();
  gemm_node2(lds, 0, 0, sch.root_dst, Wp, bias, outs, macc, row0, lane, w, lr, lg);
  __syncthreads();

  // ---- 8 layers x 2 half-batches of 4 nodes ----
  for (int l = 0; l < NLAYERS; ++l) {
#pragma unroll
    for (int h = 0; h < 2; ++h) {
      const int k0 = h * 4;
      // uniform preload of the 4 nodes' schedule entries
      const uint64_t pi0 = sch.pinfo[l * KNODES + k0 + 0];
      const uint64_t pi1 = sch.pinfo[l * KNODES + k0 + 1];
      const uint64_t pi2 = sch.pinfo[l * KNODES + k0 + 2];
      const uint64_t pi3 = sch.pinfo[l * KNODES + k0 + 3];
      const int d0 = sch.dst[l * KNODES + k0 + 0];
      const int d1 = sch.dst[l * KNODES + k0 + 1];
      const int d2 = sch.dst[l * KNODES + k0 + 2];
      const int d3 = sch.dst[l * KNODES + k0 + 3];

      // SUM phase: 4 nodes x 256 chunks = 1024 tasks over 512 threads
#pragma unroll
      for (int it = 0; it < 2; ++it) {
        const int lin = it * NTHREADS + t;
        const int nk  = lin >> 8;
        const uint64_t pinfo = (nk < 2) ? (nk == 0 ? pi0 : pi1) : (nk == 2 ? pi2 : pi3);
        const int dv         = (nk < 2) ? (nk == 0 ? d0 : d1) : (nk == 2 ? d2 : d3);
        if (dv != -3) {
          const int r = (lin >> 4) & 15, c = lin & 15;
          const int linoff = r * 256 + (c << 4);
          const int soff   = linoff ^ ((r & 7) << 4);
          float s0 = 0, s1 = 0, s2 = 0, s3 = 0, s4 = 0, s5 = 0, s6 = 0, s7 = 0;
#pragma unroll
          for (int p = 0; p < NDEG; ++p) {
            const int e  = (int)((pinfo >> (p * 16)) & 0xffff);
            const int ps = (e & 0xff) - 1;
            u32x4 v;
            if (ps >= 0) {
              v = *(const u32x4*)(lds + (size_t)ps * TILE_B + soff);
            } else {
              const int pid = e >> 8;
              v = *(const u32x4*)((const char*)(outs + (size_t)pid * NODE_ELEMS +
                                                (size_t)row0 * DIM) + linoff);
            }
            s0 += bf_lo(v.x); s1 += bf_hi(v.x);
            s2 += bf_lo(v.y); s3 += bf_hi(v.y);
            s4 += bf_lo(v.z); s5 += bf_hi(v.z);
            s6 += bf_lo(v.w); s7 += bf_hi(v.w);
          }
          u32x4 pk;
          pk.x = pack2(s0, s1); pk.y = pack2(s2, s3);
          pk.z = pack2(s4, s5); pk.w = pack2(s6, s7);
          *(u32x4*)(lds + (size_t)(SLOTS + nk) * TILE_B + soff) = pk;
        }
      }
      __syncthreads();

      // GEMM phase: 4 nodes
#pragma unroll
      for (int nk = 0; nk < 4; ++nk) {
        const int dv = (nk < 2) ? (nk == 0 ? d0 : d1) : (nk == 2 ? d2 : d3);
        const int n  = 1 + l * KNODES + k0 + nk;
        gemm_node2(lds, nk, n, dv, Wp, bias, outs, macc, row0, lane, w, lr, lg);
      }
      __syncthreads();
    }
  }

  // ---- mean store (f32) ----
  {
    const int col = w * 16 + lr;
#pragma unroll
    for (int j = 0; j < 4; ++j) {
      const int row = lg * 4 + j;
      out[(size_t)(row0 + row) * DIM + col] = macc[j];
    }
  }
}

// ---------------- host: replicate np.random.default_rng(0) graph ----------------
namespace nprng {
static inline uint32_t hashmix(uint32_t v, uint32_t& hc) {
  v ^= hc; hc *= 0x931e8875u; v *= hc; v ^= v >> 16; return v;
}
static inline uint32_t mixf(uint32_t x, uint32_t y) {
  uint32_t r = x * 0xca01f9ddu - y * 0x4973f715u;
  r ^= r >> 16;
  return r;
}
struct Pcg {
  unsigned __int128 state, inc;
  bool has32; uint32_t saved;
  void step() {
    const unsigned __int128 MUL =
        ((unsigned __int128)2549297995355413924ULL << 64) | 4865540595714422341ULL;
    state = state * MUL + inc;
  }
  void init_seed0() {
    uint32_t pool[4];
    uint32_t hc = 0x43b0d7e5u;
    for (int i = 0; i < 4; ++i) pool[i] = hashmix(0u, hc);
    for (int s = 0; s < 4; ++s)
      for (int d = 0; d < 4; ++d)
        if (s != d) pool[d] = mixf(pool[d], hashmix(pool[s], hc));
    uint32_t st[8];
    uint32_t hb = 0x8b51f9ddu;
    int cyc = 0;
    for (int i = 0; i < 8; ++i) {
      uint32_t dv = pool[cyc]; cyc = (cyc + 1) & 3;
      dv ^= hb; hb *= 0x58f38dedu; dv *= hb; dv ^= dv >> 16;
      st[i] = dv;
    }
    uint64_t v[4];
    for (int i = 0; i < 4; ++i)
      v[i] = (uint64_t)st[2 * i] | ((uint64_t)st[2 * i + 1] << 32);
    unsigned __int128 s128 = ((unsigned __int128)v[0] << 64) | v[1];
    unsigned __int128 i128 = ((unsigned __int128)v[2] << 64) | v[3];
    state = 0; inc = (i128 << 1) | 1;
    step(); state += s128; step();
    has32 = false; saved = 0;
  }
  uint64_t next64() {
    step();
    uint64_t rot = (uint64_t)(state >> 122);
    uint64_t x = (uint64_t)(state >> 64) ^ (uint64_t)state;
    return rot ? ((x >> rot) | (x << (64 - rot))) : x;
  }
  uint32_t next32() {
    if (has32) { has32 = false; return saved; }
    uint64_t v = next64();
    has32 = true; saved = (uint32_t)(v >> 32);
    return (uint32_t)v;
  }
  uint32_t lemire32(uint32_t rng_incl) {
    uint32_t rng_excl = rng_incl + 1u;
    uint64_t m = (uint64_t)next32() * (uint64_t)rng_excl;
    uint32_t leftover = (uint32_t)m;
    if (leftover < rng_excl) {
      uint32_t threshold = (0xFFFFFFFFu - rng_incl) % rng_excl;
      while (leftover < threshold) {
        m = (uint64_t)next32() * (uint64_t)rng_excl;
        leftover = (uint32_t)m;
      }
    }
    return (uint32_t)(m >> 32);
  }
};
}  // namespace nprng

extern "C" void kernel_launch(void* const* d_in, const int* in_sizes, int n_in,
                              void* d_out, int out_size, void* d_ws, size_t ws_size,
                              hipStream_t stream) {
  const float* X    = (const float*)d_in[0];
  const float* W    = (const float*)d_in[1];
  const float* bias = (const float*)d_in[2];
  float* out        = (float*)d_out;

  uint16_t* Wp   = (uint16_t*)d_ws;                                  // 2.13 MB packed W
  uint16_t* outs = (uint16_t*)((char*)d_ws + (size_t)NNODES * DIM * DIM * 2);  // spill space

  // ---- rebuild deterministic graph ----
  nprng::Pcg rng; rng.init_seed0();
  LayerSrcs srcs[NLAYERS];
  int n_prev = 1;
  for (int l = 0; l < NLAYERS; ++l) {
    for (int k = 0; k < KNODES; ++k)
      for (int j = 0; j < NDEG; ++j)
        srcs[l].p[k][j] = (n_prev == 1) ? 0 : (int)rng.lemire32((uint32_t)(n_prev - 1));
    n_prev += KNODES;
  }

  // ---- liveness: alive = contributes to the final mean ----
  bool alive[NNODES];
  for (int i = 0; i < NNODES; ++i) alive[i] = false;
  for (int i = NNODES - KNODES; i < NNODES; ++i) alive[i] = true;
  for (int l = NLAYERS - 1; l >= 0; --l)
    for (int k = 0; k < KNODES; ++k)
      if (alive[1 + l * KNODES + k])
        for (int j = 0; j < NDEG; ++j) alive[srcs[l].p[k][j]] = true;

  int last_use[NNODES];
  for (int i = 0; i < NNODES; ++i) last_use[i] = -1;
  for (int l = 0; l < NLAYERS; ++l)
    for (int k = 0; k < KNODES; ++k)
      if (alive[1 + l * KNODES + k])
        for (int j = 0; j < NDEG; ++j) {
          int s = srcs[l].p[k][j];
          if (l > last_use[s]) last_use[s] = l;
        }

  // ---- slot allocation (greedy, exact graph) ----
  int slot_of[NNODES];
  for (int i = 0; i < NNODES; ++i) slot_of[i] = -1;
  int freeStk[SLOTS], nfree = 0;
  for (int i = SLOTS - 1; i >= 0; --i) freeStk[nfree++] = i;

  Sched sch;
  slot_of[0] = freeStk[--nfree];           // node 0 always alive & first
  sch.root_dst = (int8_t)slot_of[0];

  for (int l = 0; l < NLAYERS; ++l) {
    for (int k = 0; k < KNODES; ++k) {
      const int node = 1 + l * KNODES + k;
      int dv;
      if (!alive[node])            dv = -3;
      else if (l == NLAYERS - 1)   dv = -2;                 // mean-only, reg-resident
      else if (nfree > 0)          dv = slot_of[node] = freeStk[--nfree];
      else                         dv = -1;                 // global spill
      sch.dst[l * KNODES + k] = (int8_t)dv;

      uint64_t w64 = 0;
      for (int j = 0; j < NDEG; ++j) {
        const int src = srcs[l].p[k][j];
        const int enc = ((slot_of[src] + 1) & 0xff) | (src << 8);
        w64 |= (uint64_t)enc << (j * 16);
      }
      sch.pinfo[l * KNODES + k] = w64;
    }
    // free slots whose last use was this layer (safe to reuse from layer l+1 on)
    for (int n = 0; n < NNODES; ++n)
      if (slot_of[n] >= 0 && last_use[n] == l) {
        freeStk[nfree++] = slot_of[n];
        slot_of[n] = -1;
      }
  }

  // ---- launch: 2 kernels total ----
  pack_w<<<dim3(520), dim3(256), 0, stream>>>(W, Wp);
  dag_exec<<<dim3(BATCH / ROWS), dim3(NTHREADS), 0, stream>>>(X, Wp, bias, outs, out, sch);
}

// Round 4
// 120.878 us; speedup vs baseline: 1.1456x; 1.0394x over previous
//
#include <hip/hip_runtime.h>
#include <cstdint>
#include <cstring>

#define BATCH   4096
#define DIM     128
#define NLAYERS 8
#define KNODES  8
#define NDEG    4
#define NNODES  65
#define NODE_ELEMS (BATCH * DIM)   // 524288 elems
#define ROWS    16                  // rows per block tile
#define SLOTS   37                  // LDS-resident activation slots
#define TILE_B  (ROWS * 256)        // 4096 B per bf16 tile (16 rows x 128 cols)
#define NTHREADS 1024

typedef float    f32x4 __attribute__((ext_vector_type(4)));
typedef short    s16x8 __attribute__((ext_vector_type(8)));
typedef uint32_t u32x4 __attribute__((ext_vector_type(4)));

struct LayerSrcs { int p[KNODES][NDEG]; };

struct Sched {
  uint64_t pinfo[NLAYERS * KNODES];  // per node: 4 x {slot+1 (8b), src node id (8b)}
  int8_t   dst[NLAYERS * KNODES];    // >=0 LDS slot, -1 global spill, -2 mean-only, -3 dead
  int8_t   root_dst;
};

// ---------------- device helpers ----------------
__device__ __forceinline__ uint32_t f2bf(float f) {   // RNE round to bf16
  union { float f; uint32_t i; } x; x.f = f;
  return (x.i + 0x7fffu + ((x.i >> 16) & 1u)) >> 16;
}
__device__ __forceinline__ uint32_t pack2(float a, float b) {
  return f2bf(a) | (f2bf(b) << 16);
}

// ---------------- W pre-pack: f32 row-major -> bf16 MFMA-fragment-linear ----------------
// chunk c_i = (node*4 + ks)*8 + panel; elem offset = c_i*512 + lane*8.
// element e = W[node][col = panel*16 + (lane&15)][k = ks*32 + (lane>>4)*8 + e]
__global__ __launch_bounds__(256)
void pack_w(const float* __restrict__ W, uint16_t* __restrict__ Wp) {
  int gid  = blockIdx.x * 256 + threadIdx.x;     // 65*2048 = 133120 total
  int lane = gid & 63;
  int n    = (gid >> 6) & 7;
  int ks   = (gid >> 9) & 3;
  int node = gid >> 11;
  int col  = n * 16 + (lane & 15);
  int k0   = ks * 32 + (lane >> 4) * 8;
  const float* src = W + ((size_t)node * DIM + col) * DIM + k0;
  f32x4 v0 = *(const f32x4*)src;
  f32x4 v1 = *(const f32x4*)(src + 4);
  u32x4 pk;
  pk.x = pack2(v0.x, v0.y); pk.y = pack2(v0.z, v0.w);
  pk.z = pack2(v1.x, v1.y); pk.w = pack2(v1.z, v1.w);
  *(u32x4*)(Wp + (size_t)gid * 8) = pk;
}

// ---------------- the persistent DAG executor ----------------
// 1024 threads = 16 waves = 8 nodes x 2 col-halves. One barrier per layer.
// Parent sum is folded into the MFMA accumulator (K=512 over 4 parents).
__global__ __launch_bounds__(NTHREADS)
void dag_exec(const float* __restrict__ X, const uint16_t* __restrict__ Wp,
              const float* __restrict__ bias, uint16_t* __restrict__ outs,
              float* __restrict__ out, Sched sch)
{
  __shared__ char lds[SLOTS * TILE_B + 2048 * 4];   // 37 slots + f32 mean buffer = 156 KB
  float* mb = (float*)(lds + (size_t)SLOTS * TILE_B);

  const int t    = threadIdx.x;
  const int lane = t & 63;
  const int wv   = t >> 6;
  const int lr   = lane & 15;
  const int lg   = lane >> 4;
  const int kn   = wv & 7;      // node within layer
  const int h    = wv >> 3;     // col half (64 cols)
  const int row0 = blockIdx.x * ROWS;

  mb[t] = 0.f;
  mb[t + 1024] = 0.f;

  // ---- root: node 0, A = bf16(X) read straight from global; 2 waves active ----
  if (wv < 2) {
    const int h2 = wv;
    f32x4 acc[4];
#pragma unroll
    for (int n = 0; n < 4; ++n) acc[n] = (f32x4){0.f, 0.f, 0.f, 0.f};
#pragma unroll
    for (int ks = 0; ks < 4; ++ks) {
      const float* xp = X + (size_t)(row0 + lr) * DIM + ks * 32 + lg * 8;
      f32x4 v0 = *(const f32x4*)xp;
      f32x4 v1 = *(const f32x4*)(xp + 4);
      u32x4 pk;
      pk.x = pack2(v0.x, v0.y); pk.y = pack2(v0.z, v0.w);
      pk.z = pack2(v1.x, v1.y); pk.w = pack2(v1.z, v1.w);
      s16x8 af;
      __builtin_memcpy(&af, &pk, 16);
#pragma unroll
      for (int n = 0; n < 4; ++n) {
        const size_t ci = ((size_t)(0 * 4 + ks) * 8 + h2 * 4 + n);
        s16x8 wf = *(const s16x8*)(Wp + (ci << 9) + lane * 8);
        acc[n] = __builtin_amdgcn_mfma_f32_16x16x32_bf16(af, wf, acc[n], 0, 0, 0);
      }
    }
    char* db = lds + (size_t)sch.root_dst * TILE_B;
#pragma unroll
    for (int n = 0; n < 4; ++n) {
      const int col = (h2 * 4 + n) * 16 + lr;
      const float bv = bias[col];
#pragma unroll
      for (int j = 0; j < 4; ++j) {
        const int row = lg * 4 + j;
        float v = fmaxf(acc[n][j] + bv, 0.f);
        *(uint16_t*)(db + ((row * 256 + col * 2) ^ ((row & 7) << 4))) = (uint16_t)f2bf(v);
      }
    }
  }
  __syncthreads();

  // ---- 8 layers, one wave-task per (node, col-half), one barrier per layer ----
  for (int l = 0; l < NLAYERS; ++l) {
    const int idx  = l * KNODES + kn;
    const int node = 1 + idx;
    const int dv   = sch.dst[idx];
    const uint64_t pinfo = sch.pinfo[idx];

    if (dv != -3) {
      f32x4 acc[4];
#pragma unroll
      for (int n = 0; n < 4; ++n) acc[n] = (f32x4){0.f, 0.f, 0.f, 0.f};

#pragma unroll
      for (int ks = 0; ks < 4; ++ks) {
        s16x8 af[NDEG];
#pragma unroll
        for (int p = 0; p < NDEG; ++p) {
          const int e  = (int)((pinfo >> (p * 16)) & 0xffff);
          const int ps = (e & 0xff) - 1;
          if (ps >= 0) {
            af[p] = *(const s16x8*)(lds + (size_t)ps * TILE_B +
                     ((lr * 256 + ks * 64 + lg * 16) ^ ((lr & 7) << 4)));
          } else {
            const int pid = e >> 8;
            af[p] = *(const s16x8*)(outs + (size_t)pid * NODE_ELEMS +
                     (size_t)(row0 + lr) * DIM + ks * 32 + lg * 8);
          }
        }
#pragma unroll
        for (int n = 0; n < 4; ++n) {
          const size_t ci = ((size_t)node * 4 + ks) * 8 + h * 4 + n;
          s16x8 wf = *(const s16x8*)(Wp + (ci << 9) + lane * 8);
#pragma unroll
          for (int p = 0; p < NDEG; ++p)
            acc[n] = __builtin_amdgcn_mfma_f32_16x16x32_bf16(af[p], wf, acc[n], 0, 0, 0);
        }
      }

      // epilogue
#pragma unroll
      for (int n = 0; n < 4; ++n) {
        const int col = (h * 4 + n) * 16 + lr;
        const float bv = bias[(size_t)node * DIM + col];
        if (dv >= 0) {
          char* db = lds + (size_t)dv * TILE_B;
#pragma unroll
          for (int j = 0; j < 4; ++j) {
            const int row = lg * 4 + j;
            float v = fmaxf(acc[n][j] + bv, 0.f);
            *(uint16_t*)(db + ((row * 256 + col * 2) ^ ((row & 7) << 4))) = (uint16_t)f2bf(v);
          }
        } else if (dv == -1) {
          uint16_t* gb = outs + (size_t)node * NODE_ELEMS + (size_t)row0 * DIM + col;
#pragma unroll
          for (int j = 0; j < 4; ++j) {
            const int row = lg * 4 + j;
            float v = fmaxf(acc[n][j] + bv, 0.f);
            gb[(size_t)row * DIM] = (uint16_t)f2bf(v);
          }
        } else {  // -2: accumulate into f32 mean buffer
#pragma unroll
          for (int j = 0; j < 4; ++j) {
            const int row = lg * 4 + j;
            float v = fmaxf(acc[n][j] + bv, 0.f);
            atomicAdd(mb + row * DIM + col, v);
          }
        }
      }
    }
    __syncthreads();
  }

  // ---- mean store (f32), coalesced ----
  {
    const int r = t >> 7, c = t & 127;
    out[(size_t)(row0 + r) * DIM + c]     = mb[t] * 0.125f;
    out[(size_t)(row0 + 8 + r) * DIM + c] = mb[t + 1024] * 0.125f;
  }
}

// ---------------- host: replicate np.random.default_rng(0) graph ----------------
namespace nprng {
static inline uint32_t hashmix(uint32_t v, uint32_t& hc) {
  v ^= hc; hc *= 0x931e8875u; v *= hc; v ^= v >> 16; return v;
}
static inline uint32_t mixf(uint32_t x, uint32_t y) {
  uint32_t r = x * 0xca01f9ddu - y * 0x4973f715u;
  r ^= r >> 16;
  return r;
}
struct Pcg {
  unsigned __int128 state, inc;
  bool has32; uint32_t saved;
  void step() {
    const unsigned __int128 MUL =
        ((unsigned __int128)2549297995355413924ULL << 64) | 4865540595714422341ULL;
    state = state * MUL + inc;
  }
  void init_seed0() {
    uint32_t pool[4];
    uint32_t hc = 0x43b0d7e5u;
    for (int i = 0; i < 4; ++i) pool[i] = hashmix(0u, hc);
    for (int s = 0; s < 4; ++s)
      for (int d = 0; d < 4; ++d)
        if (s != d) pool[d] = mixf(pool[d], hashmix(pool[s], hc));
    uint32_t st[8];
    uint32_t hb = 0x8b51f9ddu;
    int cyc = 0;
    for (int i = 0; i < 8; ++i) {
      uint32_t dv = pool[cyc]; cyc = (cyc + 1) & 3;
      dv ^= hb; hb *= 0x58f38dedu; dv *= hb; dv ^= dv >> 16;
      st[i] = dv;
    }
    uint64_t v[4];
    for (int i = 0; i < 4; ++i)
      v[i] = (uint64_t)st[2 * i] | ((uint64_t)st[2 * i + 1] << 32);
    unsigned __int128 s128 = ((unsigned __int128)v[0] << 64) | v[1];
    unsigned __int128 i128 = ((unsigned __int128)v[2] << 64) | v[3];
    state = 0; inc = (i128 << 1) | 1;
    step(); state += s128; step();
    has32 = false; saved = 0;
  }
  uint64_t next64() {
    step();
    uint64_t rot = (uint64_t)(state >> 122);
    uint64_t x = (uint64_t)(state >> 64) ^ (uint64_t)state;
    return rot ? ((x >> rot) | (x << (64 - rot))) : x;
  }
  uint32_t next32() {
    if (has32) { has32 = false; return saved; }
    uint64_t v = next64();
    has32 = true; saved = (uint32_t)(v >> 32);
    return (uint32_t)v;
  }
  uint32_t lemire32(uint32_t rng_incl) {
    uint32_t rng_excl = rng_incl + 1u;
    uint64_t m = (uint64_t)next32() * (uint64_t)rng_excl;
    uint32_t leftover = (uint32_t)m;
    if (leftover < rng_excl) {
      uint32_t threshold = (0xFFFFFFFFu - rng_incl) % rng_excl;
      while (leftover < threshold) {
        m = (uint64_t)next32() * (uint64_t)rng_excl;
        leftover = (uint32_t)m;
      }
    }
    return (uint32_t)(m >> 32);
  }
};
}  // namespace nprng

extern "C" void kernel_launch(void* const* d_in, const int* in_sizes, int n_in,
                              void* d_out, int out_size, void* d_ws, size_t ws_size,
                              hipStream_t stream) {
  const float* X    = (const float*)d_in[0];
  const float* W    = (const float*)d_in[1];
  const float* bias = (const float*)d_in[2];
  float* out        = (float*)d_out;

  uint16_t* Wp   = (uint16_t*)d_ws;                                  // 2.13 MB packed W
  uint16_t* outs = (uint16_t*)((char*)d_ws + (size_t)NNODES * DIM * DIM * 2);  // spill space

  // ---- rebuild deterministic graph ----
  nprng::Pcg rng; rng.init_seed0();
  LayerSrcs srcs[NLAYERS];
  int n_prev = 1;
  for (int l = 0; l < NLAYERS; ++l) {
    for (int k = 0; k < KNODES; ++k)
      for (int j = 0; j < NDEG; ++j)
        srcs[l].p[k][j] = (n_prev == 1) ? 0 : (int)rng.lemire32((uint32_t)(n_prev - 1));
    n_prev += KNODES;
  }

  // ---- liveness: alive = contributes to the final mean ----
  bool alive[NNODES];
  for (int i = 0; i < NNODES; ++i) alive[i] = false;
  for (int i = NNODES - KNODES; i < NNODES; ++i) alive[i] = true;
  for (int l = NLAYERS - 1; l >= 0; --l)
    for (int k = 0; k < KNODES; ++k)
      if (alive[1 + l * KNODES + k])
        for (int j = 0; j < NDEG; ++j) alive[srcs[l].p[k][j]] = true;

  int last_use[NNODES];
  for (int i = 0; i < NNODES; ++i) last_use[i] = -1;
  for (int l = 0; l < NLAYERS; ++l)
    for (int k = 0; k < KNODES; ++k)
      if (alive[1 + l * KNODES + k])
        for (int j = 0; j < NDEG; ++j) {
          int s = srcs[l].p[k][j];
          if (l > last_use[s]) last_use[s] = l;
        }

  // ---- slot allocation (greedy, exact graph) ----
  int slot_of[NNODES];
  for (int i = 0; i < NNODES; ++i) slot_of[i] = -1;
  int freeStk[SLOTS], nfree = 0;
  for (int i = SLOTS - 1; i >= 0; --i) freeStk[nfree++] = i;

  Sched sch;
  slot_of[0] = freeStk[--nfree];           // node 0 always alive & first
  sch.root_dst = (int8_t)slot_of[0];

  for (int l = 0; l < NLAYERS; ++l) {
    for (int k = 0; k < KNODES; ++k) {
      const int node = 1 + l * KNODES + k;
      int dv;
      if (!alive[node])            dv = -3;
      else if (l == NLAYERS - 1)   dv = -2;                 // mean-only, LDS f32 accum
      else if (nfree > 0)          dv = slot_of[node] = freeStk[--nfree];
      else                         dv = -1;                 // global spill
      sch.dst[l * KNODES + k] = (int8_t)dv;

      uint64_t w64 = 0;
      for (int j = 0; j < NDEG; ++j) {
        const int src = srcs[l].p[k][j];
        const int enc = ((slot_of[src] + 1) & 0xff) | (src << 8);
        w64 |= (uint64_t)enc << (j * 16);
      }
      sch.pinfo[l * KNODES + k] = w64;
    }
    // free slots whose last use was this layer (reusable from layer l+1 on)
    for (int n = 0; n < NNODES; ++n)
      if (slot_of[n] >= 0 && last_use[n] == l) {
        freeStk[nfree++] = slot_of[n];
        slot_of[n] = -1;
      }
  }

  // ---- launch: 2 kernels total ----
  pack_w<<<dim3(520), dim3(256), 0, stream>>>(W, Wp);
  dag_exec<<<dim3(BATCH / ROWS), dim3(NTHREADS), 0, stream>>>(X, Wp, bias, outs, out, sch);
}